// Round 11
// baseline (44.388 us; speedup 1.0000x reference)
//
#include <hip/hip_runtime.h>
#include <math.h>

typedef _Float16 f16;
typedef _Float16 f16x2 __attribute__((ext_vector_type(2)));
typedef _Float16 f16x4 __attribute__((ext_vector_type(4)));
typedef _Float16 f16x8 __attribute__((ext_vector_type(8)));
typedef float f32x4 __attribute__((ext_vector_type(4)));

#define Bn 2
#define Nn 384
#define Cc 16
#define Hh 64
#define NBk 10
#define NT 64                 // n per conv block (4 waves x 16)
#define NTILES (Nn/NT)        // 6
#define MCH 128               // m-chunks -> 128*6*2 = 1536 blocks = 6/CU, 24 waves/CU
#define MB (Nn/MCH)           // 3 m per block
#define SCALE 0.05103103630798288f   // 1/sqrt(384)
#define CP_N (MCH*NTILES*Bn*Cc)      // 24576
#define CKSP 1.1111111111111112f     // RBF center spacing 10/9

// cvt_pkrtz returns __fp16x2; bit-cast to our f16x2 (identical layout).
__device__ __forceinline__ f16x2 pkrtz(float a, float b) {
    return __builtin_bit_cast(f16x2, __builtin_amdgcn_cvt_pkrtz(a, b));
}

// LDS; tiles/scratch have disjoint live ranges (separated by barriers).
struct SM {
    union {
        __align__(16) f16   tiles[MB][1024];     // 6 KB: per-m frag-layout W2x
        __align__(16) float scratch[MB][16][64]; // 12 KB: conv2 front-A [mq][i][cp]
    } u;
    __align__(16) f16 xsf[16][16];               // conv input rows (rows >= MB zero)
    float sred[4][16];
};

// Bank-swizzle on the 16B-block index (involution; spreads g into bank bits).
__device__ __forceinline__ int swz_blk(int bi) { return bi ^ ((bi >> 4) & 3); }

// One conv pass. FIRST: xsf = masked x rows; epilogue writes f16 partials
// P[ch][b][n][i] (2 KB contiguous per block). !FIRST: xsf = chunk-reduced
// partials; epilogue masks rows + column-sums over n -> colpart.
template<bool FIRST>
__global__ __launch_bounds__(256, 6) void k_conv(
    const float* __restrict__ xyz, const float* __restrict__ w1,
    const float* __restrict__ w2, const float* __restrict__ x,
    const f16* __restrict__ pin, const int* __restrict__ mask,
    f16* __restrict__ pout, float* __restrict__ colpart)
{
    __shared__ SM sm;
    const int tid = threadIdx.x;
    const int wv = tid >> 6, l = tid & 63;
    const int g = l >> 4, c = l & 15;
    const int b = blockIdx.z, by = blockIdx.y, ch = blockIdx.x;
    const int n0 = by*NT, m0 = ch*MB;
    const int n_me = n0 + wv*16 + c;

    // zero rows MB..15 of xsf (tid 48..255 cover them exactly)
    if (tid >= MB*Cc) sm.xsf[tid >> 4][tid & 15] = (f16)0.f;

    // ---- front A: xsf[mq][i] (f16) ----
    if (FIRST) {
        if (tid < MB*Cc) {
            const int mq = tid >> 4, i = tid & 15;
            const int m = m0 + mq;
            const int keep = mask[((size_t)b*Nn + m)*Nn + m];
            sm.xsf[mq][i] = keep ? (f16)x[((size_t)b*Nn + m)*Cc + i] : (f16)0.f;
        }
    } else {
        if (tid < 192) {               // (mq in 3) x (cp in 64): sum chunks cp, cp+64
            const int mq = tid >> 6, cp = tid & 63;
            const int m = m0 + mq;
            float a[16];
            #pragma unroll
            for (int e = 0; e < 16; ++e) a[e] = 0.f;
            #pragma unroll
            for (int q = 0; q < 2; ++q) {
                const f16* pm = pin + (((size_t)(cp + q*64)*Bn + b)*Nn + m)*Cc;
                const f16x8 v0 = *reinterpret_cast<const f16x8*>(pm);
                const f16x8 v1 = *reinterpret_cast<const f16x8*>(pm + 8);
                #pragma unroll
                for (int e = 0; e < 8; ++e) { a[e] += (float)v0[e]; a[8+e] += (float)v1[e]; }
            }
            #pragma unroll
            for (int e = 0; e < 16; ++e) sm.u.scratch[mq][e][cp] = a[e];  // bank=cp: free
        }
        __syncthreads();
        if (tid < MB*Cc) {             // rotate start -> conflict-free reads
            const int mq = tid >> 4, i = tid & 15;
            float s = 0.f;
            #pragma unroll
            for (int k = 0; k < 64; ++k) s += sm.u.scratch[mq][i][(k + tid) & 63];
            sm.xsf[mq][i] = (f16)s;
        }
    }
    __syncthreads();

    // ---- front B (MFMA): per h-tile tau, D[mq][i] = sum_j xs[mq][j] * w2[tau][i*16+j]
    // A[row=mq][k=j] from xsf (1 ds_read_b64, shared by all 16 tiles of this wave);
    // B[k=j][col=i] = float4 of w2 + cvt_pkrtz. D row=4g+rr -> only g==0, rr<MB writes.
    {
        const f16x4 axs = *reinterpret_cast<const f16x4*>(&sm.xsf[c][g*4]);
        #pragma unroll 8
        for (int tt = 0; tt < 16; ++tt) {
            const int tau = wv*16 + tt;
            const float4 w = *reinterpret_cast<const float4*>(w2 + tau*256 + c*16 + g*4);
            union { f16x4 v; f16x2 h[2]; } bu;
            bu.h[0] = pkrtz(w.x, w.y);
            bu.h[1] = pkrtz(w.z, w.w);
            const f32x4 zero = {0.f, 0.f, 0.f, 0.f};
            const f32x4 d = __builtin_amdgcn_mfma_f32_16x16x16f16(axs, bu.v, zero, 0, 0, 0);
            const int fc = tau >> 5, gc = (tau >> 2) & 3;
            const int slot = (((tau >> 4) & 1) << 2) | (tau & 3);
            const int base = (swz_blk(fc*64 + gc*16 + c) << 3) | slot;
            #pragma unroll
            for (int rr = 0; rr < MB; ++rr) {   // MB<=4: row rr valid only for g==0
                if (g == 0) sm.u.tiles[rr][base] = (f16)d[rr];
            }
        }
    }

    // stage-1 A-frags: af[t][j] = (k=4g+j)<10 ? w1[k][16t+c] : 0   (w1^T tiles)
    f16x4 af[4];
    #pragma unroll
    for (int t = 0; t < 4; ++t)
        #pragma unroll
        for (int j = 0; j < 4; ++j) {
            const int k = 4*g + j;
            af[t][j] = (f16)((k < NBk) ? w1[k*Hh + 16*t + c] : 0.f);
        }

    const float* xyzb = xyz + (size_t)b*Nn*3;
    const float xn0 = xyzb[n_me*3+0], xn1 = xyzb[n_me*3+1], xn2 = xyzb[n_me*3+2];

    const int rb0 = swz_blk(l) * 8;        // swizzled read offsets (f=0, f=1)
    const int rb1 = swz_blk(64 + l) * 8;

    f32x4 acc = {0.f, 0.f, 0.f, 0.f};
    __syncthreads();                      // tiles ready; no in-loop barriers

    #pragma unroll
    for (int mi = 0; mi < MB; ++mi) {
        const float xm0 = xyzb[(m0+mi)*3+0];   // block-uniform -> scalar loads
        const float xm1 = xyzb[(m0+mi)*3+1];
        const float xm2 = xyzb[(m0+mi)*3+2];
        const float dx = xn0-xm0, dy = xn1-xm1, dz = xn2-xm2;
        const float r = sqrtf(dx*dx + dy*dy + dz*dz + 1e-12f);

        // stage-1 B-frag: rbf[n=c][k=4g+j]
        f16x4 bf;
        #pragma unroll
        for (int j = 0; j < 4; ++j) {
            const float u = r - (float)(4*g + j) * CKSP;
            bf[j] = (f16)__expf(-u*u);
        }

        const f32x4 zero = {0.f, 0.f, 0.f, 0.f};
        f32x4 h2[4];                      // h2[t][r] = hid[n=c][h=16t+4g+r]
        #pragma unroll
        for (int t = 0; t < 4; ++t)
            h2[t] = __builtin_amdgcn_mfma_f32_16x16x16f16(af[t], bf, zero, 0, 0, 0);

        // stage-2 A'-frags from LDS (pre-permuted, bank-swizzled W2x tile)
        const f16x8 a0 = *reinterpret_cast<const f16x8*>(&sm.u.tiles[mi][rb0]);
        const f16x8 a1 = *reinterpret_cast<const f16x8*>(&sm.u.tiles[mi][rb1]);

        // swish, then pack via cvt_pkrtz: bp0[j]=s[j>>2][j&3], bp1[j]=s[2+(j>>2)][j&3]
        float s[4][4];
        #pragma unroll
        for (int t = 0; t < 4; ++t)
            #pragma unroll
            for (int rr = 0; rr < 4; ++rr) {
                const float v = h2[t][rr];
                s[t][rr] = v * __builtin_amdgcn_rcpf(1.f + __expf(-v));
            }
        union { f16x8 v; f16x2 h[4]; } b0u, b1u;
        b0u.h[0] = pkrtz(s[0][0], s[0][1]);
        b0u.h[1] = pkrtz(s[0][2], s[0][3]);
        b0u.h[2] = pkrtz(s[1][0], s[1][1]);
        b0u.h[3] = pkrtz(s[1][2], s[1][3]);
        b1u.h[0] = pkrtz(s[2][0], s[2][1]);
        b1u.h[1] = pkrtz(s[2][2], s[2][3]);
        b1u.h[2] = pkrtz(s[3][0], s[3][1]);
        b1u.h[3] = pkrtz(s[3][2], s[3][3]);

        acc = __builtin_amdgcn_mfma_f32_16x16x32_f16(a0, b0u.v, acc, 0, 0, 0);
        acc = __builtin_amdgcn_mfma_f32_16x16x32_f16(a1, b1u.v, acc, 0, 0, 0);
    }

    // D: lane holds out[i = 4g+r][n = c] in acc[r]
    if (FIRST) {
        f16x4 pk;
        #pragma unroll
        for (int rr = 0; rr < 4; ++rr) pk[rr] = (f16)(acc[rr] * SCALE);
        // ch-major: block writes P[ch][b][n0..n0+63][*] = 2 KB contiguous
        *reinterpret_cast<f16x4*>(&pout[(((size_t)ch*Bn + b)*Nn + n_me)*Cc + 4*g]) = pk;
    } else {
        const int keep = mask[((size_t)b*Nn + n_me)*Nn + n_me];
        float vs[4];
        #pragma unroll
        for (int rr = 0; rr < 4; ++rr) vs[rr] = keep ? acc[rr]*SCALE : 0.f;
        #pragma unroll
        for (int d = 1; d < 16; d <<= 1) {
            #pragma unroll
            for (int rr = 0; rr < 4; ++rr) vs[rr] += __shfl_xor(vs[rr], d, 64);
        }
        if (c == 0) {
            #pragma unroll
            for (int rr = 0; rr < 4; ++rr) sm.sred[wv][4*g + rr] = vs[rr];
        }
        __syncthreads();
        if (tid < 16) {
            const float s2 = sm.sred[0][tid] + sm.sred[1][tid] + sm.sred[2][tid] + sm.sred[3][tid];
            colpart[(((size_t)ch*NTILES + by)*Bn + b)*Cc + tid] = s2;
        }
    }
}

// colpart -> colsum -> normalize (ddof=1) -> @fc2^T -> softmax
__global__ __launch_bounds__(256) void k_finalize(
    const float* __restrict__ colpart, const float* __restrict__ fc2, float* __restrict__ out)
{
    __shared__ float redf[1024];
    const int tid = threadIdx.x;
    float4 a; a.x = a.y = a.z = a.w = 0.f;
    for (int base = tid*4; base < CP_N; base += 1024) {
        const float4 v = *reinterpret_cast<const float4*>(colpart + base);
        a.x += v.x; a.y += v.y; a.z += v.z; a.w += v.w;
    }
    *reinterpret_cast<float4*>(&redf[tid*4]) = a;
    __syncthreads();
    if (tid < 32) {
        float v = 0.f;                      // flat idx ≡ b*16+i (mod 32)
        #pragma unroll
        for (int k = 0; k < 32; ++k) v += redf[tid + 32*k];
        const int i = tid & 15;             // lanes 0-15: b=0, 16-31: b=1
        float sum = v;
        #pragma unroll
        for (int d = 1; d < 16; d <<= 1) sum += __shfl_xor(sum, d, 32);
        const float mean = sum * (1.0f/16.0f);
        const float c0 = v - mean;
        float vsq = c0*c0;
        #pragma unroll
        for (int d = 1; d < 16; d <<= 1) vsq += __shfl_xor(vsq, d, 32);
        const float nv = c0 / (sqrtf(vsq * (1.0f/15.0f)) + 1e-6f);  // std ddof=1 + eps
        float y = 0.f;
        #pragma unroll
        for (int j = 0; j < 16; ++j) {
            const float nj = __shfl(nv, (tid & 16) + j, 32);
            y += nj * fc2[i*16 + j];
        }
        float mx = y;
        #pragma unroll
        for (int d = 1; d < 16; d <<= 1) mx = fmaxf(mx, __shfl_xor(mx, d, 32));
        const float e = __expf(y - mx);
        float es = e;
        #pragma unroll
        for (int d = 1; d < 16; d <<= 1) es += __shfl_xor(es, d, 32);
        out[(tid >> 4)*Cc + i] = e / es;
    }
}

extern "C" void kernel_launch(void* const* d_in, const int* in_sizes, int n_in,
                              void* d_out, int out_size, void* d_ws, size_t ws_size,
                              hipStream_t stream) {
    const float* x    = (const float*)d_in[0];
    const float* xyz  = (const float*)d_in[1];
    const int*   mask = (const int*)  d_in[2];
    const float* c1w1 = (const float*)d_in[3];
    const float* c1w2 = (const float*)d_in[4];
    const float* c2w1 = (const float*)d_in[5];
    const float* c2w2 = (const float*)d_in[6];
    const float* fc2  = (const float*)d_in[7];
    float* out = (float*)d_out;

    f16*   P  = (f16*)d_ws;                          // P[ch][b][n][i]: 3 MB
    float* CP = (float*)(P + (size_t)MCH*Bn*Nn*Cc);  // colpart: 24576 f32

    dim3 gconv(MCH, NTILES, Bn);

    k_conv<true>  <<<gconv, 256, 0, stream>>>(xyz, c1w1, c1w2, x, (const f16*)nullptr,
                                              mask, P, (float*)nullptr);
    k_conv<false> <<<gconv, 256, 0, stream>>>(xyz, c2w1, c2w2, x, (const f16*)P,
                                              mask, (f16*)nullptr, CP);
    k_finalize    <<<1, 256, 0, stream>>>(CP, fc2, out);
}

// Round 12
// 43.728 us; speedup vs baseline: 1.0151x; 1.0151x over previous
//
#include <hip/hip_runtime.h>
#include <math.h>

typedef _Float16 f16;
typedef _Float16 f16x2 __attribute__((ext_vector_type(2)));
typedef _Float16 f16x4 __attribute__((ext_vector_type(4)));
typedef _Float16 f16x8 __attribute__((ext_vector_type(8)));
typedef float f32x4 __attribute__((ext_vector_type(4)));

#define Bn 2
#define Nn 384
#define Cc 16
#define Hh 64
#define NBk 10
#define NT 192                // n per conv block (12 waves x 16)
#define NTILES (Nn/NT)        // 2
#define MCH 64                // m-chunks -> 64*2*2 = 256 blocks = exactly 1/CU
#define MB (Nn/MCH)           // 6 m per block
#define SCALE 0.05103103630798288f   // 1/sqrt(384)
#define CP_N (MCH*NTILES*Bn*Cc)      // 4096
#define CKSP 1.1111111111111112f     // RBF center spacing 10/9

// cvt_pkrtz returns __fp16x2; bit-cast to our f16x2 (identical layout).
__device__ __forceinline__ f16x2 pkrtz(float a, float b) {
    return __builtin_bit_cast(f16x2, __builtin_amdgcn_cvt_pkrtz(a, b));
}

// LDS; tiles/scratch have disjoint live ranges (separated by barriers).
struct SM {
    union {
        __align__(16) f16   tiles[MB][1024];     // 12 KB: per-m frag-layout W2x
        __align__(16) float scratch[MB][16][64]; // 24 KB: conv2 front-A [mq][i][cp]
    } u;
    __align__(16) float xsum[MB][Cc];
    float sred[12][16];
};

// Bank-swizzle on the 16B-block index (involution; spreads g into bank bits).
__device__ __forceinline__ int swz_blk(int bi) { return bi ^ ((bi >> 4) & 3); }

// Position of W2x[h][i] inside the per-m fragment tile (A' of stage-2 MFMA):
// frag f = h>>5, lane = g*16+i with g=(h>>2)&3, slot j = ((h>>4)&1)*4 + (h&3).
__device__ __forceinline__ int frag_idx(int h, int i) {
    const int f = h >> 5, g = (h >> 2) & 3, j = (((h >> 4) & 1) << 2) | (h & 3);
    return (swz_blk(f * 64 + g * 16 + i) << 3) | j;
}

// One conv pass, 768 threads (12 waves), one block per CU.
// FIRST: xsum = masked x rows; epilogue writes f16 partials P[ch][b][n][i]
// (6 KB contiguous per block). !FIRST: xsum = chunk-reduced partials;
// epilogue masks rows + column-sums over n -> colpart.
template<bool FIRST>
__global__ __launch_bounds__(768, 3) void k_conv(
    const float* __restrict__ xyz, const float* __restrict__ w1,
    const float* __restrict__ w2, const float* __restrict__ x,
    const f16* __restrict__ pin, const int* __restrict__ mask,
    f16* __restrict__ pout, float* __restrict__ colpart)
{
    __shared__ SM sm;
    const int tid = threadIdx.x;
    const int wv = tid >> 6, l = tid & 63;
    const int g = l >> 4, c = l & 15;
    const int b = blockIdx.z, by = blockIdx.y, ch = blockIdx.x;
    const int n0 = by*NT, m0 = ch*MB;
    const int n_me = n0 + wv*16 + c;

    // ---- front A: xsum[mq][i] ----
    if (FIRST) {
        if (tid < MB*Cc) {
            const int mq = tid >> 4, i = tid & 15;
            const int m = m0 + mq;
            const int keep = mask[((size_t)b*Nn + m)*Nn + m];
            sm.xsum[mq][i] = keep ? x[((size_t)b*Nn + m)*Cc + i] : 0.f;
        }
    } else {
        if (tid < MB*64) {             // (mq in 6) x (cp in 64): one strip each
            const int mq = tid >> 6, cp = tid & 63;
            const int m = m0 + mq;
            const f16* pm = pin + (((size_t)cp*Bn + b)*Nn + m)*Cc;
            const f16x8 v0 = *reinterpret_cast<const f16x8*>(pm);
            const f16x8 v1 = *reinterpret_cast<const f16x8*>(pm + 8);
            #pragma unroll
            for (int e = 0; e < 8; ++e) {
                sm.u.scratch[mq][e][cp]     = (float)v0[e];   // bank=cp: free
                sm.u.scratch[mq][8 + e][cp] = (float)v1[e];
            }
        }
        __syncthreads();
        if (tid < MB*Cc) {             // rotate start -> conflict-free reads
            const int mq = tid >> 4, i = tid & 15;
            float s = 0.f;
            #pragma unroll
            for (int k = 0; k < 64; ++k) s += sm.u.scratch[mq][i][(k + tid) & 63];
            sm.xsum[mq][i] = s;
        }
    }
    __syncthreads();

    // ---- front B (VALU): tiles[mq][frag_idx(h,i)] = (f16) sum_j w2[h][i*16+j]*xsum[mq][j]
    // 3 groups of 256 threads; group grp handles mq = 2*grp, 2*grp+1. 8 outputs/thread.
    {
        const int grp = tid >> 8, t2 = tid & 255;
        const int h = t2 >> 2, ig = t2 & 3;
        #pragma unroll
        for (int cq = 0; cq < 4; ++cq) {
            const int i = ig*4 + cq;
            const float4 wq0 = *reinterpret_cast<const float4*>(w2 + h*256 + i*16 + 0);
            const float4 wq1 = *reinterpret_cast<const float4*>(w2 + h*256 + i*16 + 4);
            const float4 wq2 = *reinterpret_cast<const float4*>(w2 + h*256 + i*16 + 8);
            const float4 wq3 = *reinterpret_cast<const float4*>(w2 + h*256 + i*16 + 12);
            const int fi = frag_idx(h, i);
            #pragma unroll
            for (int mm = 0; mm < 2; ++mm) {
                const int mq = grp*2 + mm;
                const float4 x0 = *reinterpret_cast<const float4*>(&sm.xsum[mq][0]);
                const float4 x1 = *reinterpret_cast<const float4*>(&sm.xsum[mq][4]);
                const float4 x2 = *reinterpret_cast<const float4*>(&sm.xsum[mq][8]);
                const float4 x3 = *reinterpret_cast<const float4*>(&sm.xsum[mq][12]);
                float a = wq0.x*x0.x + wq0.y*x0.y + wq0.z*x0.z + wq0.w*x0.w
                        + wq1.x*x1.x + wq1.y*x1.y + wq1.z*x1.z + wq1.w*x1.w
                        + wq2.x*x2.x + wq2.y*x2.y + wq2.z*x2.z + wq2.w*x2.w
                        + wq3.x*x3.x + wq3.y*x3.y + wq3.z*x3.z + wq3.w*x3.w;
                sm.u.tiles[mq][fi] = (f16)a;
            }
        }
    }

    // stage-1 A-frags: af[t][j] = (k=4g+j)<10 ? w1[k][16t+c] : 0   (w1^T tiles)
    f16x4 af[4];
    #pragma unroll
    for (int t = 0; t < 4; ++t)
        #pragma unroll
        for (int j = 0; j < 4; ++j) {
            const int k = 4*g + j;
            af[t][j] = (f16)((k < NBk) ? w1[k*Hh + 16*t + c] : 0.f);
        }

    const float* xyzb = xyz + (size_t)b*Nn*3;
    const float xn0 = xyzb[n_me*3+0], xn1 = xyzb[n_me*3+1], xn2 = xyzb[n_me*3+2];

    const int rb0 = swz_blk(l) * 8;        // swizzled read offsets (f=0, f=1)
    const int rb1 = swz_blk(64 + l) * 8;

    f32x4 acc = {0.f, 0.f, 0.f, 0.f};
    __syncthreads();                      // tiles ready; no in-loop barriers

    #pragma unroll
    for (int mi = 0; mi < MB; ++mi) {
        const float xm0 = xyzb[(m0+mi)*3+0];   // block-uniform -> scalar loads
        const float xm1 = xyzb[(m0+mi)*3+1];
        const float xm2 = xyzb[(m0+mi)*3+2];
        const float dx = xn0-xm0, dy = xn1-xm1, dz = xn2-xm2;
        const float r = sqrtf(dx*dx + dy*dy + dz*dz + 1e-12f);

        // stage-1 B-frag: rbf[n=c][k=4g+j]
        f16x4 bf;
        #pragma unroll
        for (int j = 0; j < 4; ++j) {
            const float u = r - (float)(4*g + j) * CKSP;
            bf[j] = (f16)__expf(-u*u);
        }

        const f32x4 zero = {0.f, 0.f, 0.f, 0.f};
        f32x4 h2[4];                      // h2[t][r] = hid[n=c][h=16t+4g+r]
        #pragma unroll
        for (int t = 0; t < 4; ++t)
            h2[t] = __builtin_amdgcn_mfma_f32_16x16x16f16(af[t], bf, zero, 0, 0, 0);

        // stage-2 A'-frags from LDS (pre-permuted, bank-swizzled W2x tile)
        const f16x8 a0 = *reinterpret_cast<const f16x8*>(&sm.u.tiles[mi][rb0]);
        const f16x8 a1 = *reinterpret_cast<const f16x8*>(&sm.u.tiles[mi][rb1]);

        // swish, then pack: bp0[j]=s[j>>2][j&3], bp1[j]=s[2+(j>>2)][j&3]
        float s[4][4];
        #pragma unroll
        for (int t = 0; t < 4; ++t)
            #pragma unroll
            for (int rr = 0; rr < 4; ++rr) {
                const float v = h2[t][rr];
                s[t][rr] = v * __builtin_amdgcn_rcpf(1.f + __expf(-v));
            }
        union { f16x8 v; f16x2 h[4]; } b0u, b1u;
        b0u.h[0] = pkrtz(s[0][0], s[0][1]);
        b0u.h[1] = pkrtz(s[0][2], s[0][3]);
        b0u.h[2] = pkrtz(s[1][0], s[1][1]);
        b0u.h[3] = pkrtz(s[1][2], s[1][3]);
        b1u.h[0] = pkrtz(s[2][0], s[2][1]);
        b1u.h[1] = pkrtz(s[2][2], s[2][3]);
        b1u.h[2] = pkrtz(s[3][0], s[3][1]);
        b1u.h[3] = pkrtz(s[3][2], s[3][3]);

        acc = __builtin_amdgcn_mfma_f32_16x16x32_f16(a0, b0u.v, acc, 0, 0, 0);
        acc = __builtin_amdgcn_mfma_f32_16x16x32_f16(a1, b1u.v, acc, 0, 0, 0);
    }

    // D: lane holds out[i = 4g+r][n = c] in acc[r]
    if (FIRST) {
        f16x4 pk;
        #pragma unroll
        for (int rr = 0; rr < 4; ++rr) pk[rr] = (f16)(acc[rr] * SCALE);
        // ch-major: block writes P[ch][b][n0..n0+191][*] = 6 KB contiguous
        *reinterpret_cast<f16x4*>(&pout[(((size_t)ch*Bn + b)*Nn + n_me)*Cc + 4*g]) = pk;
    } else {
        const int keep = mask[((size_t)b*Nn + n_me)*Nn + n_me];
        float vs[4];
        #pragma unroll
        for (int rr = 0; rr < 4; ++rr) vs[rr] = keep ? acc[rr]*SCALE : 0.f;
        #pragma unroll
        for (int d = 1; d < 16; d <<= 1) {
            #pragma unroll
            for (int rr = 0; rr < 4; ++rr) vs[rr] += __shfl_xor(vs[rr], d, 64);
        }
        if (c == 0) {
            #pragma unroll
            for (int rr = 0; rr < 4; ++rr) sm.sred[wv][4*g + rr] = vs[rr];
        }
        __syncthreads();
        if (tid < 16) {
            float s2 = 0.f;
            #pragma unroll
            for (int w = 0; w < 12; ++w) s2 += sm.sred[w][tid];
            colpart[(((size_t)ch*NTILES + by)*Bn + b)*Cc + tid] = s2;
        }
    }
}

// colpart -> colsum -> normalize (ddof=1) -> @fc2^T -> softmax
__global__ __launch_bounds__(256) void k_finalize(
    const float* __restrict__ colpart, const float* __restrict__ fc2, float* __restrict__ out)
{
    __shared__ float redf[1024];
    const int tid = threadIdx.x;
    float4 a; a.x = a.y = a.z = a.w = 0.f;
    for (int base = tid*4; base < CP_N; base += 1024) {
        const float4 v = *reinterpret_cast<const float4*>(colpart + base);
        a.x += v.x; a.y += v.y; a.z += v.z; a.w += v.w;
    }
    *reinterpret_cast<float4*>(&redf[tid*4]) = a;
    __syncthreads();
    if (tid < 32) {
        float v = 0.f;                      // flat idx ≡ b*16+i (mod 32)
        #pragma unroll
        for (int k = 0; k < 32; ++k) v += redf[tid + 32*k];
        const int i = tid & 15;             // lanes 0-15: b=0, 16-31: b=1
        float sum = v;
        #pragma unroll
        for (int d = 1; d < 16; d <<= 1) sum += __shfl_xor(sum, d, 32);
        const float mean = sum * (1.0f/16.0f);
        const float c0 = v - mean;
        float vsq = c0*c0;
        #pragma unroll
        for (int d = 1; d < 16; d <<= 1) vsq += __shfl_xor(vsq, d, 32);
        const float nv = c0 / (sqrtf(vsq * (1.0f/15.0f)) + 1e-6f);  // std ddof=1 + eps
        float y = 0.f;
        #pragma unroll
        for (int j = 0; j < 16; ++j) {
            const float nj = __shfl(nv, (tid & 16) + j, 32);
            y += nj * fc2[i*16 + j];
        }
        float mx = y;
        #pragma unroll
        for (int d = 1; d < 16; d <<= 1) mx = fmaxf(mx, __shfl_xor(mx, d, 32));
        const float e = __expf(y - mx);
        float es = e;
        #pragma unroll
        for (int d = 1; d < 16; d <<= 1) es += __shfl_xor(es, d, 32);
        out[(tid >> 4)*Cc + i] = e / es;
    }
}

extern "C" void kernel_launch(void* const* d_in, const int* in_sizes, int n_in,
                              void* d_out, int out_size, void* d_ws, size_t ws_size,
                              hipStream_t stream) {
    const float* x    = (const float*)d_in[0];
    const float* xyz  = (const float*)d_in[1];
    const int*   mask = (const int*)  d_in[2];
    const float* c1w1 = (const float*)d_in[3];
    const float* c1w2 = (const float*)d_in[4];
    const float* c2w1 = (const float*)d_in[5];
    const float* c2w2 = (const float*)d_in[6];
    const float* fc2  = (const float*)d_in[7];
    float* out = (float*)d_out;

    f16*   P  = (f16*)d_ws;                          // P[ch][b][n][i]: 1.5 MB
    float* CP = (float*)(P + (size_t)MCH*Bn*Nn*Cc);  // colpart: 4096 f32

    dim3 gconv(MCH, NTILES, Bn);

    k_conv<true>  <<<gconv, 768, 0, stream>>>(xyz, c1w1, c1w2, x, (const f16*)nullptr,
                                              mask, P, (float*)nullptr);
    k_conv<false> <<<gconv, 768, 0, stream>>>(xyz, c2w1, c2w2, x, (const f16*)P,
                                              mask, (f16*)nullptr, CP);
    k_finalize    <<<1, 256, 0, stream>>>(CP, fc2, out);
}

// Round 14
// 40.675 us; speedup vs baseline: 1.0913x; 1.0751x over previous
//
#include <hip/hip_runtime.h>
#include <math.h>

typedef _Float16 f16;
typedef _Float16 f16x4 __attribute__((ext_vector_type(4)));
typedef _Float16 f16x8 __attribute__((ext_vector_type(8)));
typedef float f32x4 __attribute__((ext_vector_type(4)));

#define Bn 2
#define Nn 384
#define Cc 16
#define Hh 64
#define NBk 10
#define NT 64                 // n per conv block (4 waves x 16)
#define NTILES (Nn/NT)        // 6
#define MCH 64                // m-chunks -> 64*6*2 = 768 blocks = 3/CU
#define MB (Nn/MCH)           // 6 m per block
#define SCALE 0.05103103630798288f   // 1/sqrt(384)
#define CP_N (MCH*NTILES*Bn*Cc)      // 12288
#define CKSP 1.1111111111111112f     // RBF center spacing 10/9

// LDS; tiles/scratch have disjoint live ranges (separated by barriers).
struct SM {
    union {
        __align__(16) f16   tiles[MB][1024];     // 12 KB: per-m frag-layout W2x
        __align__(16) float scratch[MB][16][32]; // 12 KB: conv2 front-A [mq][i][cp]
        __align__(16) float redf[1024];          // 4 KB (finalize only)
    } u;
    __align__(16) float xsum[MB][Cc];
    float sred[4][16];
};

// Bank-swizzle on the 16B-block index (involution; spreads g into bank bits).
__device__ __forceinline__ int swz_blk(int bi) { return bi ^ ((bi >> 4) & 3); }

// Position of W2x[h][i] inside the per-m fragment tile (A' of stage-2 MFMA):
// frag f = h>>5, lane = g*16+i with g=(h>>2)&3, slot j = ((h>>4)&1)*4 + (h&3).
__device__ __forceinline__ int frag_idx(int h, int i) {
    const int f = h >> 5, g = (h >> 2) & 3, j = (((h >> 4) & 1) << 2) | (h & 3);
    return (swz_blk(f * 64 + g * 16 + i) << 3) | j;
}

// One conv pass. FIRST: xsum = masked x rows; epilogue writes f16 partials
// P[ch][b][n][i] (2 KB contiguous, line-exclusive per block). !FIRST: xsum =
// chunk-reduced partials; epilogue masks rows + column-sums over n -> colpart.
template<bool FIRST>
__global__ __launch_bounds__(256, 4) void k_conv(
    const float* __restrict__ xyz, const float* __restrict__ w1,
    const float* __restrict__ w2, const float* __restrict__ x,
    const f16* __restrict__ pin, const int* __restrict__ mask,
    f16* __restrict__ pout, float* __restrict__ colpart)
{
    __shared__ SM sm;
    const int tid = threadIdx.x;
    const int wv = tid >> 6, l = tid & 63;
    const int g = l >> 4, c = l & 15;
    const int b = blockIdx.z, by = blockIdx.y, ch = blockIdx.x;
    const int n0 = by*NT, m0 = ch*MB;
    const int n_me = n0 + wv*16 + c;

    // ---- front A: xsum[mq][i] ----
    if (FIRST) {
        if (tid < MB*Cc) {
            const int mq = tid >> 4, i = tid & 15;
            const int m = m0 + mq;
            const int keep = mask[((size_t)b*Nn + m)*Nn + m];
            sm.xsum[mq][i] = keep ? x[((size_t)b*Nn + m)*Cc + i] : 0.f;
        }
    } else {
        if (tid < 192) {               // (mq, ch-pair): each sums chunks cp, cp+32
            const int mq = tid >> 5, cp = tid & 31;
            const int m = m0 + mq;
            float a[16];
            #pragma unroll
            for (int e = 0; e < 16; ++e) a[e] = 0.f;
            #pragma unroll
            for (int q = 0; q < 2; ++q) {
                const f16* pm = pin + (((size_t)(cp + q*32)*Bn + b)*Nn + m)*Cc;
                const f16x8 v0 = *reinterpret_cast<const f16x8*>(pm);
                const f16x8 v1 = *reinterpret_cast<const f16x8*>(pm + 8);
                #pragma unroll
                for (int e = 0; e < 8; ++e) { a[e] += (float)v0[e]; a[8+e] += (float)v1[e]; }
            }
            #pragma unroll
            for (int e = 0; e < 16; ++e) sm.u.scratch[mq][e][cp] = a[e];  // bank=cp: free
        }
        __syncthreads();
        if (tid < 96) {                // rotate start -> conflict-free reads
            const int mq = tid >> 4, i = tid & 15;
            float s = 0.f;
            #pragma unroll
            for (int k = 0; k < 32; ++k) s += sm.u.scratch[mq][i][(k + tid) & 31];
            sm.xsum[mq][i] = s;
        }
    }
    __syncthreads();

    // ---- front B: tiles[mq][frag_idx(h,i)] = (f16) sum_j w2[h][i*16+j]*xsum[mq][j]
    {
        const int h = tid >> 2, ig = tid & 3;
        #pragma unroll
        for (int cq = 0; cq < 4; ++cq) {
            const int i = ig*4 + cq;
            const float4 wq0 = *reinterpret_cast<const float4*>(w2 + h*256 + i*16 + 0);
            const float4 wq1 = *reinterpret_cast<const float4*>(w2 + h*256 + i*16 + 4);
            const float4 wq2 = *reinterpret_cast<const float4*>(w2 + h*256 + i*16 + 8);
            const float4 wq3 = *reinterpret_cast<const float4*>(w2 + h*256 + i*16 + 12);
            const int fi = frag_idx(h, i);
            #pragma unroll
            for (int mq = 0; mq < MB; ++mq) {
                const float4 x0 = *reinterpret_cast<const float4*>(&sm.xsum[mq][0]);
                const float4 x1 = *reinterpret_cast<const float4*>(&sm.xsum[mq][4]);
                const float4 x2 = *reinterpret_cast<const float4*>(&sm.xsum[mq][8]);
                const float4 x3 = *reinterpret_cast<const float4*>(&sm.xsum[mq][12]);
                float a = wq0.x*x0.x + wq0.y*x0.y + wq0.z*x0.z + wq0.w*x0.w
                        + wq1.x*x1.x + wq1.y*x1.y + wq1.z*x1.z + wq1.w*x1.w
                        + wq2.x*x2.x + wq2.y*x2.y + wq2.z*x2.z + wq2.w*x2.w
                        + wq3.x*x3.x + wq3.y*x3.y + wq3.z*x3.z + wq3.w*x3.w;
                sm.u.tiles[mq][fi] = (f16)a;
            }
        }
    }

    // stage-1 A-frags: af[t][j] = (k=4g+j)<10 ? w1[k][16t+c] : 0   (w1^T tiles)
    f16x4 af[4];
    #pragma unroll
    for (int t = 0; t < 4; ++t)
        #pragma unroll
        for (int j = 0; j < 4; ++j) {
            const int k = 4*g + j;
            af[t][j] = (f16)((k < NBk) ? w1[k*Hh + 16*t + c] : 0.f);
        }

    const float* xyzb = xyz + (size_t)b*Nn*3;
    const float xn0 = xyzb[n_me*3+0], xn1 = xyzb[n_me*3+1], xn2 = xyzb[n_me*3+2];

    const int rb0 = swz_blk(l) * 8;        // swizzled read offsets (f=0, f=1)
    const int rb1 = swz_blk(64 + l) * 8;

    f32x4 acc = {0.f, 0.f, 0.f, 0.f};
    __syncthreads();                      // tiles ready; no in-loop barriers

    #pragma unroll
    for (int mi = 0; mi < MB; ++mi) {
        const float xm0 = xyzb[(m0+mi)*3+0];   // block-uniform -> scalar loads
        const float xm1 = xyzb[(m0+mi)*3+1];
        const float xm2 = xyzb[(m0+mi)*3+2];
        const float dx = xn0-xm0, dy = xn1-xm1, dz = xn2-xm2;
        const float r = sqrtf(dx*dx + dy*dy + dz*dz + 1e-12f);

        // stage-1 B-frag: rbf[n=c][k=4g+j]
        f16x4 bf;
        #pragma unroll
        for (int j = 0; j < 4; ++j) {
            const float u = r - (float)(4*g + j) * CKSP;
            bf[j] = (f16)__expf(-u*u);
        }

        const f32x4 zero = {0.f, 0.f, 0.f, 0.f};
        f32x4 h2[4];                      // h2[t][r] = hid[n=c][h=16t+4g+r]
        #pragma unroll
        for (int t = 0; t < 4; ++t)
            h2[t] = __builtin_amdgcn_mfma_f32_16x16x16f16(af[t], bf, zero, 0, 0, 0);

        // stage-2 A'-frags from LDS (pre-permuted, bank-swizzled W2x tile)
        const f16x8 a0 = *reinterpret_cast<const f16x8*>(&sm.u.tiles[mi][rb0]);
        const f16x8 a1 = *reinterpret_cast<const f16x8*>(&sm.u.tiles[mi][rb1]);

        // swish + pack hid into B'-slots: slot(g,j) <-> h = 16*(2f+(j>>2)) + 4g + (j&3)
        f16x8 bp0, bp1;
        #pragma unroll
        for (int j = 0; j < 8; ++j) {
            const float v0 = h2[j>>2][j&3];
            const float v1 = h2[2 + (j>>2)][j&3];
            bp0[j] = (f16)(v0 * __builtin_amdgcn_rcpf(1.f + __expf(-v0)));
            bp1[j] = (f16)(v1 * __builtin_amdgcn_rcpf(1.f + __expf(-v1)));
        }
        acc = __builtin_amdgcn_mfma_f32_16x16x32_f16(a0, bp0, acc, 0, 0, 0);
        acc = __builtin_amdgcn_mfma_f32_16x16x32_f16(a1, bp1, acc, 0, 0, 0);
    }

    // D: lane holds out[i = 4g+r][n = c] in acc[r]
    if (FIRST) {
        f16x4 pk;
        #pragma unroll
        for (int rr = 0; rr < 4; ++rr) pk[rr] = (f16)(acc[rr] * SCALE);
        // ch-major: block writes P[ch][b][n0..n0+63][*] = 2 KB contiguous
        *reinterpret_cast<f16x4*>(&pout[(((size_t)ch*Bn + b)*Nn + n_me)*Cc + 4*g]) = pk;
    } else {
        const int keep = mask[((size_t)b*Nn + n_me)*Nn + n_me];
        float vs[4];
        #pragma unroll
        for (int rr = 0; rr < 4; ++rr) vs[rr] = keep ? acc[rr]*SCALE : 0.f;
        #pragma unroll
        for (int d = 1; d < 16; d <<= 1) {
            #pragma unroll
            for (int rr = 0; rr < 4; ++rr) vs[rr] += __shfl_xor(vs[rr], d, 64);
        }
        if (c == 0) {
            #pragma unroll
            for (int rr = 0; rr < 4; ++rr) sm.sred[wv][4*g + rr] = vs[rr];
        }
        __syncthreads();
        if (tid < 16) {
            const float s = sm.sred[0][tid] + sm.sred[1][tid] + sm.sred[2][tid] + sm.sred[3][tid];
            colpart[(((size_t)ch*NTILES + by)*Bn + b)*Cc + tid] = s;
        }
    }
}

// colpart -> colsum -> normalize (ddof=1) -> @fc2^T -> softmax
__global__ __launch_bounds__(256) void k_finalize(
    const float* __restrict__ colpart, const float* __restrict__ fc2, float* __restrict__ out)
{
    __shared__ float redf[1024];
    const int tid = threadIdx.x;
    float4 a; a.x = a.y = a.z = a.w = 0.f;
    for (int base = tid*4; base < CP_N; base += 1024) {
        const float4 v = *reinterpret_cast<const float4*>(colpart + base);
        a.x += v.x; a.y += v.y; a.z += v.z; a.w += v.w;
    }
    *reinterpret_cast<float4*>(&redf[tid*4]) = a;
    __syncthreads();
    if (tid < 32) {
        float v = 0.f;                      // flat idx ≡ b*16+i (mod 32)
        #pragma unroll
        for (int k = 0; k < 32; ++k) v += redf[tid + 32*k];
        const int i = tid & 15;             // lanes 0-15: b=0, 16-31: b=1
        float sum = v;
        #pragma unroll
        for (int d = 1; d < 16; d <<= 1) sum += __shfl_xor(sum, d, 32);
        const float mean = sum * (1.0f/16.0f);
        const float c0 = v - mean;
        float vsq = c0*c0;
        #pragma unroll
        for (int d = 1; d < 16; d <<= 1) vsq += __shfl_xor(vsq, d, 32);
        const float nv = c0 / (sqrtf(vsq * (1.0f/15.0f)) + 1e-6f);  // std ddof=1 + eps
        float y = 0.f;
        #pragma unroll
        for (int j = 0; j < 16; ++j) {
            const float nj = __shfl(nv, (tid & 16) + j, 32);
            y += nj * fc2[i*16 + j];
        }
        float mx = y;
        #pragma unroll
        for (int d = 1; d < 16; d <<= 1) mx = fmaxf(mx, __shfl_xor(mx, d, 32));
        const float e = __expf(y - mx);
        float es = e;
        #pragma unroll
        for (int d = 1; d < 16; d <<= 1) es += __shfl_xor(es, d, 32);
        out[(tid >> 4)*Cc + i] = e / es;
    }
}

extern "C" void kernel_launch(void* const* d_in, const int* in_sizes, int n_in,
                              void* d_out, int out_size, void* d_ws, size_t ws_size,
                              hipStream_t stream) {
    const float* x    = (const float*)d_in[0];
    const float* xyz  = (const float*)d_in[1];
    const int*   mask = (const int*)  d_in[2];
    const float* c1w1 = (const float*)d_in[3];
    const float* c1w2 = (const float*)d_in[4];
    const float* c2w1 = (const float*)d_in[5];
    const float* c2w2 = (const float*)d_in[6];
    const float* fc2  = (const float*)d_in[7];
    float* out = (float*)d_out;

    f16*   P  = (f16*)d_ws;                          // P[ch][b][n][i]: 1.5 MB
    float* CP = (float*)(P + (size_t)MCH*Bn*Nn*Cc);  // colpart: 12288 f32

    dim3 gconv(MCH, NTILES, Bn);

    k_conv<true>  <<<gconv, 256, 0, stream>>>(xyz, c1w1, c1w2, x, (const f16*)nullptr,
                                              mask, P, (float*)nullptr);
    k_conv<false> <<<gconv, 256, 0, stream>>>(xyz, c2w1, c2w2, x, (const f16*)P,
                                              mask, (f16*)nullptr, CP);
    k_finalize    <<<1, 256, 0, stream>>>(CP, fc2, out);
}